// Round 1
// baseline (261.511 us; speedup 1.0000x reference)
//
#include <hip/hip_runtime.h>
#include <math.h>

// ---------------- constants ----------------
#define NPIX 32768            // 2 * 128 * 128
#define OUT_DZ 0
#define OUT_BLUR 18432
#define OUT_LD 51200
#define OUT_REG 51201
#define OUT_TV 51202

__constant__ int d_cin[18] = {512,512,512,512,512,512,512,512,256,256,128,128,64,64,32,32,16,16};
__constant__ int d_H[18]   = {4,  4,  8,  16, 32, 32, 64, 64, 256,256,256,256,256,256,256,256,256,256};

struct FPtrs { const float* f[18]; };

// ws layout (float offsets)
#define WS_HA     0        // 7168
#define WS_HB     7168     // 7168
#define WS_ST     14336    // 512*16 = 8192  (-2*state transposed, [c][16])
#define WS_CN     22528    // 48: cnorm[10] @0, -2*S1[10] @16, -2*S2[10] @32
#define WS_BIASP  22576    // 18
#define WS_V      22656    // 18*512 = 9216
#define WS_CHOICE 31872    // 32768 ints
#define WS_PART   64640    // 18*32768 = 589824
#define WS_EACH   654464   // 32768
#define WS_SUMS   687232   // 128*20
#define WS_CNTS   689792   // 128*20 ints
#define WS_ATTV   692352   // 20
#define WS_TVP    692384   // 128

// ---------------- small precompute: folded attention vectors + state transpose ----------------
__global__ __launch_bounds__(512) void k_vfold(
    const float* __restrict__ afw, const float* __restrict__ afb,
    const float* __restrict__ aw,  const float* __restrict__ ab,
    const float* __restrict__ alw, const float* __restrict__ istate,
    float* __restrict__ v, float* __restrict__ biasp,
    float* __restrict__ st, float* __restrict__ cn)
{
    int t = blockIdx.x;
    if (t < 18) {
        int cin = d_cin[t];
        const float* w  = (t==0) ? afw : aw + (size_t)(t-1)*32*512;
        const float* bb = (t==0) ? afb : ab + (t-1)*32;
        float scale = (1.0f/sqrtf((float)cin)) * (1.0f/24.0f);   // 1/sqrt(cin) * 1/sqrt(576)
        int c = threadIdx.x;
        if (c < cin) {
            float s = 0.0f;
            #pragma unroll 8
            for (int o = 0; o < 32; o++) s += alw[t*32+o] * w[o*512 + c];
            v[t*512 + c] = s * scale;
        }
        if (threadIdx.x == 0) {
            float s = 0.0f;
            for (int o = 0; o < 32; o++) s += alw[t*32+o] * bb[o];
            biasp[t] = s * (1.0f/24.0f);
        }
    } else {
        int c = threadIdx.x;
        if (c < 512) {
            #pragma unroll
            for (int j = 0; j < 10; j++) st[c*16 + j] = -2.0f * istate[j*576 + c];
        }
        if (c < 10) {
            int j = c;
            float n = 0.0f, s1 = 0.0f, s2 = 0.0f;
            for (int k = 0; k < 576; k++) { float sv = istate[j*576+k]; n += sv*sv; }
            for (int k = 512; k < 544; k++) s1 += istate[j*576+k];
            for (int k = 544; k < 576; k++) s2 += istate[j*576+k];
            cn[j] = n; cn[16+j] = -2.0f*s1; cn[32+j] = -2.0f*s2;
        }
    }
}

// ---------------- cluster assignment ----------------
__global__ __launch_bounds__(256) void k_assign(
    const float* __restrict__ blend, const float* __restrict__ st,
    const float* __restrict__ cn, int* __restrict__ choice)
{
    int p = blockIdx.x*256 + threadIdx.x;
    int b = p >> 14, rem = p & 16383, y = rem >> 7, x = rem & 127;
    float cx = (float)x * (float)(2.0/127.0) - 1.0f;
    float cy = (float)y * (float)(2.0/127.0) - 1.0f;
    float g[10];
    #pragma unroll
    for (int j = 0; j < 10; j++) g[j] = cn[j] + cn[16+j]*cx + cn[32+j]*cy;
    const float* src = blend + ((size_t)b*512)*16384 + rem;
    #pragma unroll 2
    for (int c = 0; c < 512; c++) {
        float val = src[(size_t)c << 14];
        #pragma unroll
        for (int j = 0; j < 10; j++) g[j] = fmaf(val, st[c*16 + j], g[j]);
    }
    int best = 0; float bg = g[0];
    #pragma unroll
    for (int j = 1; j < 10; j++) if (g[j] < bg) { bg = g[j]; best = j; }
    choice[p] = b*10 + best;
}

// ---------------- mapper: RMS norm ----------------
__global__ __launch_bounds__(256) void k_norm(const float* __restrict__ x, float* __restrict__ h)
{
    int r = blockIdx.x;           // 0..13  (b*7+c)
    int b = r / 7, c = r % 7;
    const float* xr = x + ((size_t)b*18 + c)*512;
    int tid = threadIdx.x;
    float v0 = xr[tid], v1 = xr[tid+256];
    __shared__ float red[256];
    __shared__ float scale;
    red[tid] = v0*v0 + v1*v1; __syncthreads();
    for (int s = 128; s; s >>= 1) { if (tid < s) red[tid] += red[tid+s]; __syncthreads(); }
    if (tid == 0) scale = 1.0f / sqrtf(red[0]*(1.0f/512.0f) + 1e-8f);
    __syncthreads();
    h[r*512 + tid] = v0*scale; h[r*512 + 256 + tid] = v1*scale;
}

// ---------------- mapper: one MLP layer (wave per (c,o), both batches) ----------------
__global__ __launch_bounds__(256) void k_mlp(
    const float* __restrict__ mw, const float* __restrict__ mb,
    const float* __restrict__ hin, float* __restrict__ hout,
    int layer, float* __restrict__ dz)
{
    int wave = blockIdx.x*4 + (threadIdx.x >> 6);
    int lane = threadIdx.x & 63;
    int c = wave >> 9, o = wave & 511;
    const float* wrow = mw + (((size_t)(c*3 + layer)*512 + o) << 9) + lane*8;
    float4 w0 = *(const float4*)wrow;
    float4 w1 = *(const float4*)(wrow + 4);
    const float* h0 = hin + (size_t)c*512 + lane*8;
    const float* h1 = hin + (size_t)(7 + c)*512 + lane*8;
    float4 a0 = *(const float4*)h0, a1 = *(const float4*)(h0+4);
    float4 b0 = *(const float4*)h1, b1 = *(const float4*)(h1+4);
    float d0 = a0.x*w0.x + a0.y*w0.y + a0.z*w0.z + a0.w*w0.w
             + a1.x*w1.x + a1.y*w1.y + a1.z*w1.z + a1.w*w1.w;
    float d1 = b0.x*w0.x + b0.y*w0.y + b0.z*w0.z + b0.w*w0.w
             + b1.x*w1.x + b1.y*w1.y + b1.z*w1.z + b1.w*w1.w;
    #pragma unroll
    for (int m = 32; m; m >>= 1) { d0 += __shfl_xor(d0, m); d1 += __shfl_xor(d1, m); }
    if (lane == 0) {
        const float wsc = (float)(0.1/22.62741699796952);   // 0.1/sqrt(512)
        const float rt2 = 1.41421356237309515f;
        float bias = mb[(c*3 + layer)*512 + o] * 0.1f;
        float z0 = d0*wsc + bias; z0 = (z0 > 0.0f ? z0 : 0.2f*z0) * rt2;
        float z1 = d1*wsc + bias; z1 = (z1 > 0.0f ? z1 : 0.2f*z1) * rt2;
        hout[(size_t)c*512 + o] = z0;
        hout[(size_t)(7 + c)*512 + o] = z1;
        if (dz) {
            dz[((size_t)0*18 + c)*512 + o] = z0;
            dz[((size_t)1*18 + c)*512 + o] = z1;
        }
    }
}

// ---------------- loss_delta ----------------
__global__ __launch_bounds__(256) void k_lossdelta(const float* __restrict__ h, float* __restrict__ outp)
{
    __shared__ float red[256];
    int tid = threadIdx.x;
    float total = 0.0f;
    for (int r = 0; r < 14; r++) {
        float v0 = h[r*512 + tid], v1 = h[r*512 + 256 + tid];
        red[tid] = v0*v0 + v1*v1; __syncthreads();
        for (int s = 128; s; s >>= 1) { if (tid < s) red[tid] += red[tid+s]; __syncthreads(); }
        if (tid == 0) total += sqrtf(red[0]);
        __syncthreads();
    }
    if (tid == 0) outp[0] = total * (1.0f/14.0f);
}

// ---------------- zero tail of delta_zs (layers 7..17) ----------------
__global__ __launch_bounds__(256) void k_zero(float* __restrict__ out)
{
    int z = blockIdx.x*256 + threadIdx.x;   // 0..11263
    if (z < 11264) {
        int b = z / (11*512), rem = z % (11*512);
        out[(size_t)b*18*512 + 7*512 + rem] = 0.0f;
    }
}

// ---------------- per-layer folded attention dot (4 pixels/thread) ----------------
__global__ __launch_bounds__(256) void k_each(FPtrs fp, const float* __restrict__ v, float* __restrict__ partial)
{
    int t = blockIdx.y;
    int cin = d_cin[t], H = d_H[t];
    const float* vt = v + t*512;
    int p0 = blockIdx.x*1024 + threadIdx.x;
    float acc[4] = {0,0,0,0};
    const float* srcs[4];
    size_t HH = (size_t)H * H;
    #pragma unroll
    for (int k = 0; k < 4; k++) {
        int p = p0 + k*256;
        int b = p >> 14, rem = p & 16383, y = rem >> 7, x = rem & 127;
        int sy = (y*H) >> 7, sx = (x*H) >> 7;
        srcs[k] = fp.f[t] + ((size_t)b*cin)*HH + (size_t)sy*H + sx;
    }
    #pragma unroll 4
    for (int c = 0; c < cin; c++) {
        float vv = vt[c];
        size_t off = (size_t)c * HH;
        #pragma unroll
        for (int k = 0; k < 4; k++) acc[k] = fmaf(srcs[k][off], vv, acc[k]);
    }
    #pragma unroll
    for (int k = 0; k < 4; k++) partial[(size_t)t*NPIX + p0 + k*256] = acc[k];
}

// ---------------- logits -> sigmoid -> segment partials ----------------
__global__ __launch_bounds__(256) void k_logits(
    const float* __restrict__ partial, const float* __restrict__ biasp,
    const float* __restrict__ alb, const int* __restrict__ choice,
    float* __restrict__ each, float* __restrict__ bsums, int* __restrict__ bcnts)
{
    __shared__ float ssum[20]; __shared__ int scnt[20]; __shared__ float sbias;
    int tid = threadIdx.x;
    if (tid < 20) { ssum[tid] = 0.0f; scnt[tid] = 0; }
    if (tid == 0) {
        float s = alb[0];
        for (int t = 0; t < 18; t++) s += biasp[t];
        sbias = s;
    }
    __syncthreads();
    int p = blockIdx.x*256 + tid;
    float lg = sbias;
    #pragma unroll
    for (int t = 0; t < 18; t++) lg += partial[(size_t)t*NPIX + p];
    float e = 1.0f / (1.0f + expf(-lg));
    each[p] = e;
    int ch = choice[p];
    atomicAdd(&ssum[ch], e);
    atomicAdd(&scnt[ch], 1);
    __syncthreads();
    if (tid < 20) { bsums[blockIdx.x*20 + tid] = ssum[tid]; bcnts[blockIdx.x*20 + tid] = scnt[tid]; }
}

// ---------------- segment stats -> attval, loss_reg ----------------
__global__ __launch_bounds__(64) void k_stats(
    const float* __restrict__ bsums, const int* __restrict__ bcnts,
    float* __restrict__ attv, float* __restrict__ out)
{
    __shared__ float red[32];
    int j = threadIdx.x;
    float regj = 0.0f;
    if (j < 20) {
        float s = 0.0f; int c = 0;
        for (int blk = 0; blk < 128; blk++) { s += bsums[blk*20 + j]; c += bcnts[blk*20 + j]; }
        float mean = s / fmaxf((float)c, 1.0f);
        attv[j] = (c > 0) ? mean : 1.0f;
        regj = (c > 0) ? fmaxf(mean - 0.8f, 0.0f) : 0.0f;
    }
    if (j < 32) red[j] = (j < 20) ? regj : 0.0f;
    __syncthreads();
    for (int s = 16; s; s >>= 1) { if (j < s) red[j] += red[j+s]; __syncthreads(); }
    if (j == 0) out[OUT_REG] = red[0] * 0.5f;   // / batch
}

// ---------------- final map, blur, loss_tv partials ----------------
__global__ __launch_bounds__(256) void k_final(
    const float* __restrict__ each, const int* __restrict__ choice,
    const float* __restrict__ attv, float* __restrict__ tvp, float* __restrict__ out)
{
    __shared__ float av[20];
    __shared__ float red[256];
    int tid = threadIdx.x;
    if (tid < 20) av[tid] = attv[tid];
    __syncthreads();
    int p = blockIdx.x*256 + tid;
    int b = p >> 14, rem = p & 16383, y = rem >> 7, x = rem & 127;
    // gaussian weights (computed exactly as reference does, in f32)
    float k1[5]; float ks = 0.0f;
    #pragma unroll
    for (int i = 0; i < 5; i++) { float d = (float)(i-2) / 1.1f; k1[i] = expf(-0.5f*d*d); ks += k1[i]; }
    #pragma unroll
    for (int i = 0; i < 5; i++) k1[i] /= ks;
    const int* cb = choice + b*16384;
    float acc = 0.0f;
    #pragma unroll
    for (int a = 0; a < 5; a++) {
        int yy = y + a - 2; yy = (yy < 0) ? -yy : ((yy > 127) ? 254 - yy : yy);
        #pragma unroll
        for (int bb = 0; bb < 5; bb++) {
            int xx = x + bb - 2; xx = (xx < 0) ? -xx : ((xx > 127) ? 254 - xx : xx);
            float am = av[cb[yy*128 + xx]];
            float fin = (am < 0.8f) ? 0.0f : am;
            acc += k1[a]*k1[bb]*fin;
        }
    }
    out[OUT_BLUR + p] = acc;
    float amc = av[cb[y*128 + x]];
    float d = each[p] - amc;
    red[tid] = d*d; __syncthreads();
    for (int s = 128; s; s >>= 1) { if (tid < s) red[tid] += red[tid+s]; __syncthreads(); }
    if (tid == 0) tvp[blockIdx.x] = red[0];
}

__global__ __launch_bounds__(128) void k_tvred(const float* __restrict__ tvp, float* __restrict__ out)
{
    __shared__ float red[128];
    int tid = threadIdx.x;
    red[tid] = tvp[tid]; __syncthreads();
    for (int s = 64; s; s >>= 1) { if (tid < s) red[tid] += red[tid+s]; __syncthreads(); }
    if (tid == 0) out[OUT_TV] = red[0] * (1.0f/32768.0f);
}

// ---------------- host ----------------
extern "C" void kernel_launch(void* const* d_in, const int* in_sizes, int n_in,
                              void* d_out, int out_size, void* d_ws, size_t ws_size,
                              hipStream_t stream)
{
    const float* x      = (const float*)d_in[0];
    const float* blend  = (const float*)d_in[11];   // fmap_10
    const float* mw     = (const float*)d_in[27];
    const float* mb     = (const float*)d_in[28];
    const float* afw    = (const float*)d_in[29];
    const float* afb    = (const float*)d_in[30];
    const float* aw     = (const float*)d_in[31];
    const float* ab     = (const float*)d_in[32];
    const float* alw    = (const float*)d_in[33];
    const float* alb    = (const float*)d_in[34];
    const float* istate = (const float*)d_in[35];
    float* out = (float*)d_out;
    float* ws  = (float*)d_ws;

    static const int LN[17] = {0,2,3,5,6,8,9,11,12,14,15,17,18,20,21,23,24};
    FPtrs fp;
    fp.f[0] = (const float*)d_in[26];               // fmap_25
    for (int c = 0; c < 17; c++) fp.f[1+c] = (const float*)d_in[1 + LN[c]];

    float* hA     = ws + WS_HA;
    float* hB     = ws + WS_HB;
    float* st     = ws + WS_ST;
    float* cn     = ws + WS_CN;
    float* biasp  = ws + WS_BIASP;
    float* v      = ws + WS_V;
    int*   choice = (int*)(ws + WS_CHOICE);
    float* part   = ws + WS_PART;
    float* each   = ws + WS_EACH;
    float* bsums  = ws + WS_SUMS;
    int*   bcnts  = (int*)(ws + WS_CNTS);
    float* attv   = ws + WS_ATTV;
    float* tvp    = ws + WS_TVP;

    k_vfold<<<dim3(19), 512, 0, stream>>>(afw, afb, aw, ab, alw, istate, v, biasp, st, cn);
    k_norm<<<14, 256, 0, stream>>>(x, hA);
    k_mlp<<<896, 256, 0, stream>>>(mw, mb, hA, hB, 0, nullptr);
    k_mlp<<<896, 256, 0, stream>>>(mw, mb, hB, hA, 1, nullptr);
    k_mlp<<<896, 256, 0, stream>>>(mw, mb, hA, hB, 2, out + OUT_DZ);
    k_lossdelta<<<1, 256, 0, stream>>>(hB, out + OUT_LD);
    k_zero<<<44, 256, 0, stream>>>(out);
    k_assign<<<128, 256, 0, stream>>>(blend, st, cn, choice);
    k_each<<<dim3(32, 18), 256, 0, stream>>>(fp, v, part);
    k_logits<<<128, 256, 0, stream>>>(part, biasp, alb, choice, each, bsums, bcnts);
    k_stats<<<1, 64, 0, stream>>>(bsums, bcnts, attv, out);
    k_final<<<128, 256, 0, stream>>>(each, choice, attv, tvp, out);
    k_tvred<<<1, 128, 0, stream>>>(tvp, out);
}

// Round 2
// 168.188 us; speedup vs baseline: 1.5549x; 1.5549x over previous
//
#include <hip/hip_runtime.h>
#include <math.h>

// ---------------- constants ----------------
#define NPIX 32768            // 2 * 128 * 128
#define OUT_DZ 0
#define OUT_BLUR 18432
#define OUT_LD 51200
#define OUT_REG 51201
#define OUT_TV 51202

__constant__ int d_cin[18] = {512,512,512,512,512,512,512,512,256,256,128,128,64,64,32,32,16,16};
__constant__ int d_H[18]   = {4,  4,  8,  16, 32, 32, 64, 64, 256,256,256,256,256,256,256,256,256,256};

struct FPtrs { const float* f[18]; };

// ws layout (float offsets)
#define WS_HA     0        // 7168
#define WS_HB     7168     // 7168
#define WS_ST     14336    // 512*16 = 8192  (-2*state transposed, [c][16])
#define WS_CN     22528    // 48: cnorm[10] @0, -2*S1[10] @16, -2*S2[10] @32
#define WS_BIASP  22576    // 18
#define WS_V      22656    // 18*512 = 9216
#define WS_CHOICE 31872    // 32768 ints
#define WS_PART   64640    // 18*32768 = 589824
#define WS_EACH   654464   // 32768
#define WS_SUMS   687232   // 128*20
#define WS_CNTS   689792   // 128*20 ints
#define WS_ATTV   692352   // 20
#define WS_TVP    692384   // 128

// ---------------- small precompute: folded attention vectors + state transpose ----------------
__global__ __launch_bounds__(512) void k_vfold(
    const float* __restrict__ afw, const float* __restrict__ afb,
    const float* __restrict__ aw,  const float* __restrict__ ab,
    const float* __restrict__ alw, const float* __restrict__ istate,
    float* __restrict__ v, float* __restrict__ biasp,
    float* __restrict__ st, float* __restrict__ cn)
{
    int t = blockIdx.x;
    if (t < 18) {
        int cin = d_cin[t];
        const float* w  = (t==0) ? afw : aw + (size_t)(t-1)*32*512;
        const float* bb = (t==0) ? afb : ab + (t-1)*32;
        float scale = (1.0f/sqrtf((float)cin)) * (1.0f/24.0f);   // 1/sqrt(cin) * 1/sqrt(576)
        int c = threadIdx.x;
        if (c < cin) {
            float s = 0.0f;
            #pragma unroll 8
            for (int o = 0; o < 32; o++) s += alw[t*32+o] * w[o*512 + c];
            v[t*512 + c] = s * scale;
        }
        if (threadIdx.x == 0) {
            float s = 0.0f;
            for (int o = 0; o < 32; o++) s += alw[t*32+o] * bb[o];
            biasp[t] = s * (1.0f/24.0f);
        }
    } else {
        int c = threadIdx.x;
        if (c < 512) {
            #pragma unroll
            for (int j = 0; j < 10; j++) st[c*16 + j] = -2.0f * istate[j*576 + c];
        }
        if (c < 10) {
            int j = c;
            float n = 0.0f, s1 = 0.0f, s2 = 0.0f;
            for (int k = 0; k < 576; k++) { float sv = istate[j*576+k]; n += sv*sv; }
            for (int k = 512; k < 544; k++) s1 += istate[j*576+k];
            for (int k = 544; k < 576; k++) s2 += istate[j*576+k];
            cn[j] = n; cn[16+j] = -2.0f*s1; cn[32+j] = -2.0f*s2;
        }
    }
}

// ---------------- cluster assignment (split-K in-block) ----------------
// 64 pixels per block, 4 waves each owning a 128-channel chunk; LDS reduce.
__global__ __launch_bounds__(256) void k_assign(
    const float* __restrict__ blend, const float* __restrict__ st,
    const float* __restrict__ cn, int* __restrict__ choice)
{
    __shared__ float gsh[256*10];
    int tid = threadIdx.x;
    // wave-uniform channel chunk (readfirstlane -> SGPR -> st loads become s_load)
    int csub = __builtin_amdgcn_readfirstlane(tid >> 6);
    int pl = tid & 63;
    int p = blockIdx.x*64 + pl;
    int b = p >> 14, rem = p & 16383;
    float g[10] = {0,0,0,0,0,0,0,0,0,0};
    const float* src = blend + ((size_t)b*512 + csub*128)*16384 + rem;
    const float* stc = st + csub*128*16;
    #pragma unroll 8
    for (int c = 0; c < 128; c++) {
        float val = src[(size_t)c << 14];
        #pragma unroll
        for (int j = 0; j < 10; j++) g[j] = fmaf(val, stc[c*16 + j], g[j]);
    }
    #pragma unroll
    for (int j = 0; j < 10; j++) gsh[tid*10 + j] = g[j];
    __syncthreads();
    if (tid < 64) {
        int pp = blockIdx.x*64 + tid;
        int bb = pp >> 14, rr = pp & 16383, y = rr >> 7, x = rr & 127;
        float cx = (float)x * (float)(2.0/127.0) - 1.0f;
        float cy = (float)y * (float)(2.0/127.0) - 1.0f;
        float gt[10];
        #pragma unroll
        for (int j = 0; j < 10; j++) {
            gt[j] = cn[j] + cn[16+j]*cx + cn[32+j]*cy
                  + gsh[tid*10 + j] + gsh[(64+tid)*10 + j]
                  + gsh[(128+tid)*10 + j] + gsh[(192+tid)*10 + j];
        }
        int best = 0; float bg = gt[0];
        #pragma unroll
        for (int j = 1; j < 10; j++) if (gt[j] < bg) { bg = gt[j]; best = j; }
        choice[pp] = bb*10 + best;
    }
}

// ---------------- mapper: RMS norm ----------------
__global__ __launch_bounds__(256) void k_norm(const float* __restrict__ x, float* __restrict__ h)
{
    int r = blockIdx.x;           // 0..13  (b*7+c)
    int b = r / 7, c = r % 7;
    const float* xr = x + ((size_t)b*18 + c)*512;
    int tid = threadIdx.x;
    float v0 = xr[tid], v1 = xr[tid+256];
    __shared__ float red[256];
    __shared__ float scale;
    red[tid] = v0*v0 + v1*v1; __syncthreads();
    for (int s = 128; s; s >>= 1) { if (tid < s) red[tid] += red[tid+s]; __syncthreads(); }
    if (tid == 0) scale = 1.0f / sqrtf(red[0]*(1.0f/512.0f) + 1e-8f);
    __syncthreads();
    h[r*512 + tid] = v0*scale; h[r*512 + 256 + tid] = v1*scale;
}

// ---------------- mapper: one MLP layer (wave per (c,o), both batches) ----------------
__global__ __launch_bounds__(256) void k_mlp(
    const float* __restrict__ mw, const float* __restrict__ mb,
    const float* __restrict__ hin, float* __restrict__ hout,
    int layer, float* __restrict__ dz)
{
    int wave = blockIdx.x*4 + (threadIdx.x >> 6);
    int lane = threadIdx.x & 63;
    int c = wave >> 9, o = wave & 511;
    const float* wrow = mw + (((size_t)(c*3 + layer)*512 + o) << 9) + lane*8;
    float4 w0 = *(const float4*)wrow;
    float4 w1 = *(const float4*)(wrow + 4);
    const float* h0 = hin + (size_t)c*512 + lane*8;
    const float* h1 = hin + (size_t)(7 + c)*512 + lane*8;
    float4 a0 = *(const float4*)h0, a1 = *(const float4*)(h0+4);
    float4 b0 = *(const float4*)h1, b1 = *(const float4*)(h1+4);
    float d0 = a0.x*w0.x + a0.y*w0.y + a0.z*w0.z + a0.w*w0.w
             + a1.x*w1.x + a1.y*w1.y + a1.z*w1.z + a1.w*w1.w;
    float d1 = b0.x*w0.x + b0.y*w0.y + b0.z*w0.z + b0.w*w0.w
             + b1.x*w1.x + b1.y*w1.y + b1.z*w1.z + b1.w*w1.w;
    #pragma unroll
    for (int m = 32; m; m >>= 1) { d0 += __shfl_xor(d0, m); d1 += __shfl_xor(d1, m); }
    if (lane == 0) {
        const float wsc = (float)(0.1/22.62741699796952);   // 0.1/sqrt(512)
        const float rt2 = 1.41421356237309515f;
        float bias = mb[(c*3 + layer)*512 + o] * 0.1f;
        float z0 = d0*wsc + bias; z0 = (z0 > 0.0f ? z0 : 0.2f*z0) * rt2;
        float z1 = d1*wsc + bias; z1 = (z1 > 0.0f ? z1 : 0.2f*z1) * rt2;
        hout[(size_t)c*512 + o] = z0;
        hout[(size_t)(7 + c)*512 + o] = z1;
        if (dz) {
            dz[((size_t)0*18 + c)*512 + o] = z0;
            dz[((size_t)1*18 + c)*512 + o] = z1;
        }
    }
}

// ---------------- loss_delta ----------------
__global__ __launch_bounds__(256) void k_lossdelta(const float* __restrict__ h, float* __restrict__ outp)
{
    __shared__ float red[256];
    int tid = threadIdx.x;
    float total = 0.0f;
    for (int r = 0; r < 14; r++) {
        float v0 = h[r*512 + tid], v1 = h[r*512 + 256 + tid];
        red[tid] = v0*v0 + v1*v1; __syncthreads();
        for (int s = 128; s; s >>= 1) { if (tid < s) red[tid] += red[tid+s]; __syncthreads(); }
        if (tid == 0) total += sqrtf(red[0]);
        __syncthreads();
    }
    if (tid == 0) outp[0] = total * (1.0f/14.0f);
}

// ---------------- zero tail of delta_zs (layers 7..17) ----------------
__global__ __launch_bounds__(256) void k_zero(float* __restrict__ out)
{
    int z = blockIdx.x*256 + threadIdx.x;   // 0..11263
    if (z < 11264) {
        int b = z / (11*512), rem = z % (11*512);
        out[(size_t)b*18*512 + 7*512 + rem] = 0.0f;
    }
}

// ---------------- per-layer folded attention dot (4 pixels/thread) ----------------
__global__ __launch_bounds__(256) void k_each(FPtrs fp, const float* __restrict__ v, float* __restrict__ partial)
{
    int t = blockIdx.y;
    int cin = d_cin[t], H = d_H[t];
    const float* vt = v + t*512;
    int p0 = blockIdx.x*1024 + threadIdx.x;
    float acc[4] = {0,0,0,0};
    const float* srcs[4];
    size_t HH = (size_t)H * H;
    #pragma unroll
    for (int k = 0; k < 4; k++) {
        int p = p0 + k*256;
        int b = p >> 14, rem = p & 16383, y = rem >> 7, x = rem & 127;
        int sy = (y*H) >> 7, sx = (x*H) >> 7;
        srcs[k] = fp.f[t] + ((size_t)b*cin)*HH + (size_t)sy*H + sx;
    }
    #pragma unroll 4
    for (int c = 0; c < cin; c++) {
        float vv = vt[c];
        size_t off = (size_t)c * HH;
        #pragma unroll
        for (int k = 0; k < 4; k++) acc[k] = fmaf(srcs[k][off], vv, acc[k]);
    }
    #pragma unroll
    for (int k = 0; k < 4; k++) partial[(size_t)t*NPIX + p0 + k*256] = acc[k];
}

// ---------------- logits -> sigmoid -> segment partials ----------------
__global__ __launch_bounds__(256) void k_logits(
    const float* __restrict__ partial, const float* __restrict__ biasp,
    const float* __restrict__ alb, const int* __restrict__ choice,
    float* __restrict__ each, float* __restrict__ bsums, int* __restrict__ bcnts)
{
    __shared__ float ssum[20]; __shared__ int scnt[20]; __shared__ float sbias;
    int tid = threadIdx.x;
    if (tid < 20) { ssum[tid] = 0.0f; scnt[tid] = 0; }
    if (tid == 0) {
        float s = alb[0];
        for (int t = 0; t < 18; t++) s += biasp[t];
        sbias = s;
    }
    __syncthreads();
    int p = blockIdx.x*256 + tid;
    float lg = sbias;
    #pragma unroll
    for (int t = 0; t < 18; t++) lg += partial[(size_t)t*NPIX + p];
    float e = 1.0f / (1.0f + expf(-lg));
    each[p] = e;
    int ch = choice[p];
    atomicAdd(&ssum[ch], e);
    atomicAdd(&scnt[ch], 1);
    __syncthreads();
    if (tid < 20) { bsums[blockIdx.x*20 + tid] = ssum[tid]; bcnts[blockIdx.x*20 + tid] = scnt[tid]; }
}

// ---------------- segment stats -> attval, loss_reg ----------------
__global__ __launch_bounds__(64) void k_stats(
    const float* __restrict__ bsums, const int* __restrict__ bcnts,
    float* __restrict__ attv, float* __restrict__ out)
{
    __shared__ float red[32];
    int j = threadIdx.x;
    float regj = 0.0f;
    if (j < 20) {
        float s = 0.0f; int c = 0;
        for (int blk = 0; blk < 128; blk++) { s += bsums[blk*20 + j]; c += bcnts[blk*20 + j]; }
        float mean = s / fmaxf((float)c, 1.0f);
        attv[j] = (c > 0) ? mean : 1.0f;
        regj = (c > 0) ? fmaxf(mean - 0.8f, 0.0f) : 0.0f;
    }
    if (j < 32) red[j] = (j < 20) ? regj : 0.0f;
    __syncthreads();
    for (int s = 16; s; s >>= 1) { if (j < s) red[j] += red[j+s]; __syncthreads(); }
    if (j == 0) out[OUT_REG] = red[0] * 0.5f;   // / batch
}

// ---------------- final map, blur, loss_tv partials ----------------
__global__ __launch_bounds__(256) void k_final(
    const float* __restrict__ each, const int* __restrict__ choice,
    const float* __restrict__ attv, float* __restrict__ tvp, float* __restrict__ out)
{
    __shared__ float av[20];
    __shared__ float red[256];
    int tid = threadIdx.x;
    if (tid < 20) av[tid] = attv[tid];
    __syncthreads();
    int p = blockIdx.x*256 + tid;
    int b = p >> 14, rem = p & 16383, y = rem >> 7, x = rem & 127;
    // gaussian weights (computed exactly as reference does, in f32)
    float k1[5]; float ks = 0.0f;
    #pragma unroll
    for (int i = 0; i < 5; i++) { float d = (float)(i-2) / 1.1f; k1[i] = expf(-0.5f*d*d); ks += k1[i]; }
    #pragma unroll
    for (int i = 0; i < 5; i++) k1[i] /= ks;
    const int* cb = choice + b*16384;
    float acc = 0.0f;
    #pragma unroll
    for (int a = 0; a < 5; a++) {
        int yy = y + a - 2; yy = (yy < 0) ? -yy : ((yy > 127) ? 254 - yy : yy);
        #pragma unroll
        for (int bb = 0; bb < 5; bb++) {
            int xx = x + bb - 2; xx = (xx < 0) ? -xx : ((xx > 127) ? 254 - xx : xx);
            float am = av[cb[yy*128 + xx]];
            float fin = (am < 0.8f) ? 0.0f : am;
            acc += k1[a]*k1[bb]*fin;
        }
    }
    out[OUT_BLUR + p] = acc;
    float amc = av[cb[y*128 + x]];
    float d = each[p] - amc;
    red[tid] = d*d; __syncthreads();
    for (int s = 128; s; s >>= 1) { if (tid < s) red[tid] += red[tid+s]; __syncthreads(); }
    if (tid == 0) tvp[blockIdx.x] = red[0];
}

__global__ __launch_bounds__(128) void k_tvred(const float* __restrict__ tvp, float* __restrict__ out)
{
    __shared__ float red[128];
    int tid = threadIdx.x;
    red[tid] = tvp[tid]; __syncthreads();
    for (int s = 64; s; s >>= 1) { if (tid < s) red[tid] += red[tid+s]; __syncthreads(); }
    if (tid == 0) out[OUT_TV] = red[0] * (1.0f/32768.0f);
}

// ---------------- host ----------------
extern "C" void kernel_launch(void* const* d_in, const int* in_sizes, int n_in,
                              void* d_out, int out_size, void* d_ws, size_t ws_size,
                              hipStream_t stream)
{
    const float* x      = (const float*)d_in[0];
    const float* blend  = (const float*)d_in[11];   // fmap_10
    const float* mw     = (const float*)d_in[27];
    const float* mb     = (const float*)d_in[28];
    const float* afw    = (const float*)d_in[29];
    const float* afb    = (const float*)d_in[30];
    const float* aw     = (const float*)d_in[31];
    const float* ab     = (const float*)d_in[32];
    const float* alw    = (const float*)d_in[33];
    const float* alb    = (const float*)d_in[34];
    const float* istate = (const float*)d_in[35];
    float* out = (float*)d_out;
    float* ws  = (float*)d_ws;

    static const int LN[17] = {0,2,3,5,6,8,9,11,12,14,15,17,18,20,21,23,24};
    FPtrs fp;
    fp.f[0] = (const float*)d_in[26];               // fmap_25
    for (int c = 0; c < 17; c++) fp.f[1+c] = (const float*)d_in[1 + LN[c]];

    float* hA     = ws + WS_HA;
    float* hB     = ws + WS_HB;
    float* st     = ws + WS_ST;
    float* cn     = ws + WS_CN;
    float* biasp  = ws + WS_BIASP;
    float* v      = ws + WS_V;
    int*   choice = (int*)(ws + WS_CHOICE);
    float* part   = ws + WS_PART;
    float* each   = ws + WS_EACH;
    float* bsums  = ws + WS_SUMS;
    int*   bcnts  = (int*)(ws + WS_CNTS);
    float* attv   = ws + WS_ATTV;
    float* tvp    = ws + WS_TVP;

    k_vfold<<<dim3(19), 512, 0, stream>>>(afw, afb, aw, ab, alw, istate, v, biasp, st, cn);
    k_norm<<<14, 256, 0, stream>>>(x, hA);
    k_mlp<<<896, 256, 0, stream>>>(mw, mb, hA, hB, 0, nullptr);
    k_mlp<<<896, 256, 0, stream>>>(mw, mb, hB, hA, 1, nullptr);
    k_mlp<<<896, 256, 0, stream>>>(mw, mb, hA, hB, 2, out + OUT_DZ);
    k_lossdelta<<<1, 256, 0, stream>>>(hB, out + OUT_LD);
    k_zero<<<44, 256, 0, stream>>>(out);
    k_assign<<<512, 256, 0, stream>>>(blend, st, cn, choice);
    k_each<<<dim3(32, 18), 256, 0, stream>>>(fp, v, part);
    k_logits<<<128, 256, 0, stream>>>(part, biasp, alb, choice, each, bsums, bcnts);
    k_stats<<<1, 64, 0, stream>>>(bsums, bcnts, attv, out);
    k_final<<<128, 256, 0, stream>>>(each, choice, attv, tvp, out);
    k_tvred<<<1, 128, 0, stream>>>(tvp, out);
}